// Round 3
// baseline (369.999 us; speedup 1.0000x reference)
//
#include <hip/hip_runtime.h>
#include <hip/hip_bf16.h>
#include <hip/hip_cooperative_groups.h>

namespace cg = cooperative_groups;

#define BB 32
#define SS 1024
#define HHH 768
#define EE 128
#define WW 8
#define PP 512
#define RDD 32

typedef __attribute__((ext_vector_type(8))) short bf16x8;
typedef __attribute__((ext_vector_type(8))) unsigned short us8;
typedef __attribute__((ext_vector_type(4))) unsigned short us4;
typedef __attribute__((ext_vector_type(4))) float f32x4;

__device__ __forceinline__ unsigned short f2bf(float v) {
    __hip_bfloat16 h = __float2bfloat16(v);
    return *(unsigned short*)&h;
}

// ---------------------------------------------------------------------------
// K1: merged pool + prep (unchanged).
// ---------------------------------------------------------------------------
__global__ __launch_bounds__(256) void pool_prep_kernel(
    const float* __restrict__ seq, const int* __restrict__ starts,
    const int* __restrict__ types, const float* __restrict__ temb,
    unsigned short* __restrict__ xout,
    const float* __restrict__ W1, unsigned short* __restrict__ Wt,
    const float* __restrict__ Wr1, unsigned short* __restrict__ Wtr,
    const float* __restrict__ W2, unsigned short* __restrict__ W2t,
    const float* __restrict__ remb, unsigned short* __restrict__ rembb,
    float* __restrict__ basep) {
    int tid = threadIdx.x;
    __shared__ float sbuf[WW * HHH];
    __shared__ float scred[WW];
    __shared__ float attn_s[WW];

    if (blockIdx.x < BB * EE) {
        int be = blockIdx.x;
        int b = be >> 7;
        int start = starts[be];
        const float4* bp4 = (const float4*)(seq + ((size_t)b * SS + start) * HHH);
        for (int idx = tid; idx < WW * (HHH / 4); idx += 256) {
            int w = idx / (HHH / 4), h4 = idx % (HHH / 4);
            float4 v = bp4[(size_t)w * (HHH / 4) + h4];
            sbuf[w * HHH + h4 * 4 + 0] = v.x; sbuf[w * HHH + h4 * 4 + 1] = v.y;
            sbuf[w * HHH + h4 * 4 + 2] = v.z; sbuf[w * HHH + h4 * 4 + 3] = v.w;
        }
        __syncthreads();

        float sc[WW];
#pragma unroll
        for (int w = 0; w < WW; w++) sc[w] = 0.f;
#pragma unroll
        for (int c = 0; c < 3; c++) {
            int h = tid + 256 * c;
            float s = 0.f;
#pragma unroll
            for (int w = 0; w < WW; w++) s += sbuf[w * HHH + h];
            float m = s * (1.0f / WW);
#pragma unroll
            for (int w = 0; w < WW; w++) sc[w] += sbuf[w * HHH + h] * m;
        }
        if (tid < WW) scred[tid] = 0.f;
        __syncthreads();
        int lane = tid & 63;
#pragma unroll
        for (int w = 0; w < WW; w++) {
            float v = sc[w];
            for (int o = 32; o > 0; o >>= 1) v += __shfl_down(v, o, 64);
            if (lane == 0) atomicAdd(&scred[w], v);
        }
        __syncthreads();
        if (tid == 0) {
            float mx = scred[0];
            for (int w = 1; w < WW; w++) mx = fmaxf(mx, scred[w]);
            float ssum = 0.f;
            float a[WW];
            for (int w = 0; w < WW; w++) { a[w] = __expf(scred[w] - mx); ssum += a[w]; }
            float inv = 1.f / ssum;
            for (int w = 0; w < WW; w++) attn_s[w] = a[w] * inv;
        }
        __syncthreads();

        int t = types[be];
        const float* emb = temb + (size_t)t * HHH;
#pragma unroll
        for (int c = 0; c < 3; c++) {
            int h = tid + 256 * c;
            float p = 0.f;
#pragma unroll
            for (int w = 0; w < WW; w++) p += attn_s[w] * sbuf[w * HHH + h];
            xout[(size_t)be * HHH + h] = f2bf(p + emb[h]);
        }
        return;
    }

    int blk = blockIdx.x - BB * EE;
    if (blk < 48) {
        int k0 = blk * 16;
        for (int i = tid; i < 16 * 256; i += 256)
            sbuf[i] = W1[(size_t)(k0 + (i >> 8)) * 256 + (i & 255)];
        __syncthreads();
        int n = tid;
        us8 v0, v1;
#pragma unroll
        for (int kk = 0; kk < 8; kk++) v0[kk] = f2bf(sbuf[kk * 256 + n]);
#pragma unroll
        for (int kk = 0; kk < 8; kk++) v1[kk] = f2bf(sbuf[(8 + kk) * 256 + n]);
        *(us8*)(Wt + (size_t)n * HHH + k0) = v0;
        *(us8*)(Wt + (size_t)n * HHH + k0 + 8) = v1;
    } else if (blk < 58) {
        int k0 = (blk - 48) * 16;
        for (int i = tid; i < 16 * 256; i += 256)
            sbuf[i] = Wr1[(size_t)(k0 + (i >> 8)) * 256 + (i & 255)];
        __syncthreads();
        int n = tid;
        us8 v0, v1;
#pragma unroll
        for (int kk = 0; kk < 8; kk++) v0[kk] = f2bf(sbuf[kk * 256 + n]);
#pragma unroll
        for (int kk = 0; kk < 8; kk++) v1[kk] = f2bf(sbuf[(8 + kk) * 256 + n]);
        *(us8*)(Wtr + (size_t)n * 160 + k0) = v0;
        *(us8*)(Wtr + (size_t)n * 160 + k0 + 8) = v1;
    } else if (blk < 74) {
        int k0 = (blk - 58) * 16;
        for (int i = tid; i < 16 * 64; i += 256)
            sbuf[(i >> 6) * 64 + (i & 63)] = W2[(size_t)(k0 + (i >> 6)) * 64 + (i & 63)];
        __syncthreads();
        if (tid < 64) {
            int n = tid;
            us8 v0, v1;
#pragma unroll
            for (int kk = 0; kk < 8; kk++) v0[kk] = f2bf(sbuf[kk * 64 + n]);
#pragma unroll
            for (int kk = 0; kk < 8; kk++) v1[kk] = f2bf(sbuf[(8 + kk) * 64 + n]);
            *(us8*)(W2t + (size_t)n * 256 + k0) = v0;
            *(us8*)(W2t + (size_t)n * 256 + k0 + 8) = v1;
        }
    } else if (blk == 74) {
        for (int i = tid; i < 9 * RDD; i += 256) rembb[i] = f2bf(remb[i]);
    } else {
        int pc = blk - 75;
        int kc = pc % 12;
        int b = pc / 12;
        int n = tid;
        if (n < 64) sbuf[4096 + n] = seq[(size_t)b * SS * HHH + kc * 64 + n];
        __syncthreads();
        float acc = 0.f;
        const float* w = Wr1 + (size_t)(160 + kc * 64) * 256 + n;
#pragma unroll 16
        for (int k = 0; k < 64; k++) acc += sbuf[4096 + k] * w[(size_t)k * 256];
        basep[((size_t)kc * 32 + b) * 256 + n] = acc;
    }
}

// ---------------------------------------------------------------------------
// Fused K2+K3+K4+K5: one cooperative launch, 256 blocks x 256 threads,
// 3 grid syncs. LDS union max ~44 KB (P4) -> 3 blocks/CU headroom; the
// cooperative launch only needs 1/CU. P2/P3 read MFMA B-operands straight
// from global (L2/L3-hot) instead of LDS slabs to keep the union small.
// ---------------------------------------------------------------------------
struct SmP1 {
    unsigned short As[64][40];
    unsigned short Bs[64][40];
    unsigned short T[64][72];
    float sdred[64][2][2];
};
struct SmP2 {
    float ssh[2][128];
    float dsh[2][128];
    float lnred[32][2][2];
    unsigned short g1s[32][264];
    float sdr2[32][2][2];
    unsigned short t2[64][40];
};
struct SmP3 {
    float ssh[128];
    float dsh[128];
};
struct SmP4 {
    unsigned short As[64][168];
    unsigned short Bs[256][40];
    float sred[64][4];
    int prs[64][3];
};
union SmU {
    SmP1 p1;
    SmP2 p2;
    SmP3 p3;
    SmP4 p4;
};

struct FusedParams {
    const unsigned short* Xb;
    const unsigned short* Wt;
    const float* asrc1;
    const float* adst1;
    unsigned short* h1Tg;
    float* ps_s;
    float* ps_d;
    const float* b1;
    const float* ln1g;
    const float* ln1b;
    const unsigned short* W2t;
    const float* asrc2;
    const float* adst2;
    unsigned short* h2Tg;
    float* s2;
    float* d2;
    const float* b2v;
    const float* ln2g;
    const float* ln2b;
    unsigned short* x2b;
    const float* basep;
    const float* br1;
    const int* pair_idx;
    const int* rel_ids;
    const unsigned short* rembb;
    const unsigned short* Wtr;
    const float* Wr2;
    const float* br2;
    float* out;
};

__global__ __launch_bounds__(256) void fused_mid_kernel(FusedParams p) {
    __shared__ __align__(16) SmU sm;
    cg::grid_group grid = cg::this_grid();
    int bid = blockIdx.x;
    int tid = threadIdx.x;
    int wave = tid >> 6, lane = tid & 63;
    int fr = lane & 15;
    int fk = (lane >> 4) * 8;
    int crow = (lane >> 4) * 4;
    int ccol = lane & 15;

    // =====================================================================
    // P1: GEMM1 (Xb @ Wt^T) + fused sd1 dots + bf16 transposed h1Tg.
    // =====================================================================
    {
        const int K = HHH;
        int n0 = (bid & 3) * 64;
        int m0 = (bid >> 2) * 64;
        int wm = (wave >> 1) * 32, wn = (wave & 1) * 32;

        f32x4 acc[2][2] = {};
        int ar = tid >> 2;
        int ac = (tid & 3) * 8;

        for (int k0 = 0; k0 < K; k0 += 32) {
            us8 av = *(const us8*)(p.Xb + (size_t)(m0 + ar) * K + k0 + ac);
            us8 bv = *(const us8*)(p.Wt + (size_t)(n0 + ar) * K + k0 + ac);
            *(us8*)(&sm.p1.As[ar][ac]) = av;
            *(us8*)(&sm.p1.Bs[ar][ac]) = bv;
            __syncthreads();

            bf16x8 a0 = *(const bf16x8*)(&sm.p1.As[wm + fr][fk]);
            bf16x8 a1 = *(const bf16x8*)(&sm.p1.As[wm + 16 + fr][fk]);
            bf16x8 b0 = *(const bf16x8*)(&sm.p1.Bs[wn + fr][fk]);
            bf16x8 b1 = *(const bf16x8*)(&sm.p1.Bs[wn + 16 + fr][fk]);

            acc[0][0] = __builtin_amdgcn_mfma_f32_16x16x32_bf16(a0, b0, acc[0][0], 0, 0, 0);
            acc[0][1] = __builtin_amdgcn_mfma_f32_16x16x32_bf16(a0, b1, acc[0][1], 0, 0, 0);
            acc[1][0] = __builtin_amdgcn_mfma_f32_16x16x32_bf16(a1, b0, acc[1][0], 0, 0, 0);
            acc[1][1] = __builtin_amdgcn_mfma_f32_16x16x32_bf16(a1, b1, acc[1][1], 0, 0, 0);
            __syncthreads();
        }

        int h = n0 >> 7;
        int nb = (n0 >> 6) & 1;
        int dbase = (n0 & 127) + wn;

        float asv[2], adv[2];
#pragma unroll
        for (int ni = 0; ni < 2; ni++) {
            int d = dbase + ni * 16 + ccol;
            asv[ni] = p.asrc1[h * 128 + d];
            adv[ni] = p.adst1[h * 128 + d];
        }

#pragma unroll
        for (int mi = 0; mi < 2; mi++) {
#pragma unroll
            for (int r = 0; r < 4; r++) {
                float sp = 0.f, dp = 0.f;
#pragma unroll
                for (int ni = 0; ni < 2; ni++) {
                    float v = acc[mi][ni][r];
                    sm.p1.T[wn + ni * 16 + ccol][wm + mi * 16 + crow + r] = f2bf(v);
                    sp += v * asv[ni];
                    dp += v * adv[ni];
                }
                for (int msk = 1; msk < 16; msk <<= 1) {
                    sp += __shfl_xor(sp, msk, 64);
                    dp += __shfl_xor(dp, msk, 64);
                }
                if ((lane & 15) == 0) {
                    int row = wm + mi * 16 + crow + r;
                    sm.p1.sdred[row][wn >> 5][0] = sp;
                    sm.p1.sdred[row][wn >> 5][1] = dp;
                }
            }
        }
        __syncthreads();

        int b = m0 >> 7;
        int j0 = m0 & 127;
        if (tid < 64) {
            float spt = sm.p1.sdred[tid][0][0] + sm.p1.sdred[tid][1][0];
            float dpt = sm.p1.sdred[tid][0][1] + sm.p1.sdred[tid][1][1];
            size_t o = (size_t)nb * 8192 + ((size_t)(m0 + tid)) * 2 + h;
            p.ps_s[o] = spt;
            p.ps_d[o] = dpt;
        }
        {
            int d_l = tid >> 2, q = tid & 3;
            us8 v0 = *(const us8*)(&sm.p1.T[d_l][q * 16]);
            us8 v1 = *(const us8*)(&sm.p1.T[d_l][q * 16 + 8]);
            size_t go = ((size_t)(b * 2 + h) * 128 + (n0 & 127) + d_l) * 128 + j0 + q * 16;
            *(us8*)(p.h1Tg + go) = v0;
            *(us8*)(p.h1Tg + go + 8) = v1;
        }
    }
    grid.sync();

    // =====================================================================
    // P2: GAT1 + LN + ELU + GEMM2 + sd2 (blocks 0..127).
    // =====================================================================
    if (bid < 128) {
        int b = bid >> 2;
        int c = bid & 3;
        int h = wave >> 1, m = wave & 1;

        {
            int hh = tid >> 7, j = tid & 127;
            size_t o = ((size_t)b * 128 + j) * 2 + hh;
            sm.p2.ssh[hh][j] = p.ps_s[o] + p.ps_s[o + 8192];
            sm.p2.dsh[hh][j] = p.ps_d[o] + p.ps_d[o + 8192];
        }
        __syncthreads();

        bf16x8 afrag[4];
        {
            float dd = sm.p2.dsh[h][c * 32 + m * 16 + fr];
            float ev[4][8];
            float mx = -1e30f;
#pragma unroll
            for (int ks = 0; ks < 4; ks++)
#pragma unroll
                for (int jj = 0; jj < 8; jj++) {
                    float e = dd + sm.p2.ssh[h][ks * 32 + fk + jj];
                    e = e >= 0.f ? e : 0.2f * e;
                    ev[ks][jj] = e;
                    mx = fmaxf(mx, e);
                }
            mx = fmaxf(mx, __shfl_xor(mx, 16, 64));
            mx = fmaxf(mx, __shfl_xor(mx, 32, 64));
            float sq = 0.f;
#pragma unroll
            for (int ks = 0; ks < 4; ks++)
#pragma unroll
                for (int jj = 0; jj < 8; jj++) {
                    float e = __expf(ev[ks][jj] - mx);
                    ev[ks][jj] = e;
                    sq += e;
                }
            sq += __shfl_xor(sq, 16, 64);
            sq += __shfl_xor(sq, 32, 64);
            float inv = 1.f / sq;
#pragma unroll
            for (int ks = 0; ks < 4; ks++) {
                bf16x8 a;
#pragma unroll
                for (int jj = 0; jj < 8; jj++)
                    a[jj] = (short)f2bf(ev[ks][jj] * inv);
                afrag[ks] = a;
            }
        }

        // PV MFMA: B-operand straight from global h1Tg (L2/L3-hot)
        const unsigned short* hb = p.h1Tg + ((size_t)(b * 2 + h) * 128) * 128;
        f32x4 acc[8] = {};
#pragma unroll
        for (int ks = 0; ks < 4; ks++)
#pragma unroll
            for (int ni = 0; ni < 8; ni++) {
                bf16x8 bv = *(const bf16x8*)(hb + (size_t)(ni * 16 + fr) * 128 +
                                             ks * 32 + fk);
                acc[ni] = __builtin_amdgcn_mfma_f32_16x16x32_bf16(
                    afrag[ks], bv, acc[ni], 0, 0, 0);
            }

        float bv_[8], gv[8], bev[8];
#pragma unroll
        for (int ni = 0; ni < 8; ni++) {
            int d = h * 128 + ni * 16 + ccol;
            bv_[ni] = p.b1[d]; gv[ni] = p.ln1g[d]; bev[ni] = p.ln1b[d];
        }
        float vv[4][8];
#pragma unroll
        for (int r = 0; r < 4; r++) {
            float s = 0.f, q = 0.f;
#pragma unroll
            for (int ni = 0; ni < 8; ni++) {
                float v = acc[ni][r] + bv_[ni];
                vv[r][ni] = v;
                s += v;
                q += v * v;
            }
            s += __shfl_xor(s, 1, 64); s += __shfl_xor(s, 2, 64);
            s += __shfl_xor(s, 4, 64); s += __shfl_xor(s, 8, 64);
            q += __shfl_xor(q, 1, 64); q += __shfl_xor(q, 2, 64);
            q += __shfl_xor(q, 4, 64); q += __shfl_xor(q, 8, 64);
            if ((lane & 15) == 0) {
                sm.p2.lnred[m * 16 + crow + r][h][0] = s;
                sm.p2.lnred[m * 16 + crow + r][h][1] = q;
            }
        }
        __syncthreads();
#pragma unroll
        for (int r = 0; r < 4; r++) {
            int row = m * 16 + crow + r;
            float s = sm.p2.lnred[row][0][0] + sm.p2.lnred[row][1][0];
            float q = sm.p2.lnred[row][0][1] + sm.p2.lnred[row][1][1];
            float mean = s * (1.f / 256.f);
            float var = q * (1.f / 256.f) - mean * mean;
            float rs = rsqrtf(var + 1e-5f);
#pragma unroll
            for (int ni = 0; ni < 8; ni++) {
                float y = (vv[r][ni] - mean) * rs * gv[ni] + bev[ni];
                y = y > 0.f ? y : (__expf(y) - 1.f);
                sm.p2.g1s[row][h * 128 + ni * 16 + ccol] = f2bf(y);
            }
        }
        __syncthreads();

        // GEMM2: g1s(32x256) @ W2t^T with fused s2/d2 dots
        int m2 = wave & 1;
        int nb = wave >> 1;
        f32x4 acc2[2] = {};
#pragma unroll
        for (int kc = 0; kc < 8; kc++) {
            bf16x8 a = *(const bf16x8*)(&sm.p2.g1s[m2 * 16 + fr][kc * 32 + fk]);
#pragma unroll
            for (int ni = 0; ni < 2; ni++) {
                bf16x8 wv = *(const bf16x8*)(p.W2t + (size_t)(nb * 32 + ni * 16 + fr) * 256 +
                                             kc * 32 + fk);
                acc2[ni] = __builtin_amdgcn_mfma_f32_16x16x32_bf16(a, wv, acc2[ni], 0, 0, 0);
            }
        }
        float as2[2], ad2[2];
#pragma unroll
        for (int ni = 0; ni < 2; ni++) {
            int n = nb * 32 + ni * 16 + ccol;
            as2[ni] = p.asrc2[n];
            ad2[ni] = p.adst2[n];
        }
#pragma unroll
        for (int r = 0; r < 4; r++) {
            int rl = m2 * 16 + crow + r;
            float sp = 0.f, dp = 0.f;
#pragma unroll
            for (int ni = 0; ni < 2; ni++) {
                float v = acc2[ni][r];
                sm.p2.t2[nb * 32 + ni * 16 + ccol][rl] = f2bf(v);
                sp += v * as2[ni];
                dp += v * ad2[ni];
            }
            for (int msk = 1; msk < 16; msk <<= 1) {
                sp += __shfl_xor(sp, msk, 64);
                dp += __shfl_xor(dp, msk, 64);
            }
            if ((lane & 15) == 0) {
                sm.p2.sdr2[rl][nb][0] = sp;
                sm.p2.sdr2[rl][nb][1] = dp;
            }
        }
        __syncthreads();
        if (tid < 32) {
            p.s2[(size_t)b * 128 + c * 32 + tid] =
                sm.p2.sdr2[tid][0][0] + sm.p2.sdr2[tid][1][0];
            p.d2[(size_t)b * 128 + c * 32 + tid] =
                sm.p2.sdr2[tid][0][1] + sm.p2.sdr2[tid][1][1];
        }
        {
            int d = tid >> 2, q = tid & 3;
            us8 v = *(const us8*)(&sm.p2.t2[d][q * 8]);
            *(us8*)(p.h2Tg + ((size_t)b * 64 + d) * 128 + c * 32 + q * 8) = v;
        }
    }
    grid.sync();

    // =====================================================================
    // P3: GAT2 + LN(64) + ELU (blocks 0..63).
    // =====================================================================
    if (bid < 64) {
        int b = bid >> 1;
        int c = bid & 1;

        {
            if (tid < 128) sm.p3.ssh[tid] = p.s2[(size_t)b * 128 + tid];
            else sm.p3.dsh[tid - 128] = p.d2[(size_t)b * 128 + (tid - 128)];
        }
        __syncthreads();

        bf16x8 afrag[4];
        {
            float dd = sm.p3.dsh[c * 64 + wave * 16 + fr];
            float ev[4][8];
            float mx = -1e30f;
#pragma unroll
            for (int ks = 0; ks < 4; ks++)
#pragma unroll
                for (int jj = 0; jj < 8; jj++) {
                    float e = dd + sm.p3.ssh[ks * 32 + fk + jj];
                    e = e >= 0.f ? e : 0.2f * e;
                    ev[ks][jj] = e;
                    mx = fmaxf(mx, e);
                }
            mx = fmaxf(mx, __shfl_xor(mx, 16, 64));
            mx = fmaxf(mx, __shfl_xor(mx, 32, 64));
            float sq = 0.f;
#pragma unroll
            for (int ks = 0; ks < 4; ks++)
#pragma unroll
                for (int jj = 0; jj < 8; jj++) {
                    float e = __expf(ev[ks][jj] - mx);
                    ev[ks][jj] = e;
                    sq += e;
                }
            sq += __shfl_xor(sq, 16, 64);
            sq += __shfl_xor(sq, 32, 64);
            float inv = 1.f / sq;
#pragma unroll
            for (int ks = 0; ks < 4; ks++) {
                bf16x8 a;
#pragma unroll
                for (int jj = 0; jj < 8; jj++)
                    a[jj] = (short)f2bf(ev[ks][jj] * inv);
                afrag[ks] = a;
            }
        }

        // PV MFMA: B-operand straight from global h2Tg
        const unsigned short* hb2 = p.h2Tg + (size_t)b * 64 * 128;
        f32x4 acc[4] = {};
#pragma unroll
        for (int ks = 0; ks < 4; ks++)
#pragma unroll
            for (int ni = 0; ni < 4; ni++) {
                bf16x8 bv = *(const bf16x8*)(hb2 + (size_t)(ni * 16 + fr) * 128 +
                                             ks * 32 + fk);
                acc[ni] = __builtin_amdgcn_mfma_f32_16x16x32_bf16(
                    afrag[ks], bv, acc[ni], 0, 0, 0);
            }

        float bv_[4], gv[4], bev[4];
#pragma unroll
        for (int ni = 0; ni < 4; ni++) {
            int d = ni * 16 + ccol;
            bv_[ni] = p.b2v[d]; gv[ni] = p.ln2g[d]; bev[ni] = p.ln2b[d];
        }
#pragma unroll
        for (int r = 0; r < 4; r++) {
            float v[4];
            float s = 0.f;
#pragma unroll
            for (int ni = 0; ni < 4; ni++) {
                v[ni] = acc[ni][r] + bv_[ni];
                s += v[ni];
            }
            s += __shfl_xor(s, 1, 64); s += __shfl_xor(s, 2, 64);
            s += __shfl_xor(s, 4, 64); s += __shfl_xor(s, 8, 64);
            float mean = s * (1.f / 64.f);
            float sq = 0.f;
#pragma unroll
            for (int ni = 0; ni < 4; ni++) {
                float dv = v[ni] - mean;
                sq += dv * dv;
            }
            sq += __shfl_xor(sq, 1, 64); sq += __shfl_xor(sq, 2, 64);
            sq += __shfl_xor(sq, 4, 64); sq += __shfl_xor(sq, 8, 64);
            float rs = rsqrtf(sq * (1.f / 64.f) + 1e-5f);
            int i = c * 64 + wave * 16 + crow + r;
            unsigned short* dst = p.x2b + (size_t)(b * 128 + i) * 64;
#pragma unroll
            for (int ni = 0; ni < 4; ni++) {
                float y = (v[ni] - mean) * rs * gv[ni] + bev[ni];
                y = y > 0.f ? y : (__expf(y) - 1.f);
                dst[ni * 16 + ccol] = f2bf(y);
            }
        }
    }
    grid.sync();

    // =====================================================================
    // P4: pair scores (all 256 blocks).
    // =====================================================================
    {
        int b = bid >> 3;
        int p0 = (bid & 7) * 64;
        int wn = wave * 64;

        if (tid < 64) {
            int pp = p0 + tid;
            sm.p4.prs[tid][0] = p.pair_idx[((size_t)b * PP + pp) * 2 + 0];
            sm.p4.prs[tid][1] = p.pair_idx[((size_t)b * PP + pp) * 2 + 1];
            sm.p4.prs[tid][2] = p.rel_ids[(size_t)b * PP + pp];
        }
        __syncthreads();
        for (int it = 0; it < 10; it++) {
            int idx = tid + it * 256;
            int m = idx / 40, c = idx % 40;
            int k0 = c * 4;
            us4 v;
            if (k0 < 64)
                v = *(const us4*)(p.x2b + ((size_t)b * EE + sm.p4.prs[m][0]) * 64 + k0);
            else if (k0 < 128)
                v = *(const us4*)(p.x2b + ((size_t)b * EE + sm.p4.prs[m][1]) * 64 + (k0 - 64));
            else
                v = *(const us4*)(p.rembb + sm.p4.prs[m][2] * RDD + (k0 - 128));
            *(us4*)(&sm.p4.As[m][k0]) = v;
        }

        f32x4 acc[4][4] = {};
        for (int kc = 0; kc < 5; kc++) {
            for (int it = 0; it < 4; it++) {
                int i = tid + it * 256;
                int n = i >> 2, c = i & 3;
                *(us8*)(&sm.p4.Bs[n][c * 8]) =
                    *(const us8*)(p.Wtr + (size_t)n * 160 + kc * 32 + c * 8);
            }
            __syncthreads();
            bf16x8 a[4], bv[4];
#pragma unroll
            for (int mi = 0; mi < 4; mi++)
                a[mi] = *(const bf16x8*)(&sm.p4.As[mi * 16 + fr][kc * 32 + fk]);
#pragma unroll
            for (int ni = 0; ni < 4; ni++)
                bv[ni] = *(const bf16x8*)(&sm.p4.Bs[wn + ni * 16 + fr][fk]);
#pragma unroll
            for (int mi = 0; mi < 4; mi++)
#pragma unroll
                for (int ni = 0; ni < 4; ni++)
                    acc[mi][ni] = __builtin_amdgcn_mfma_f32_16x16x32_bf16(
                        a[mi], bv[ni], acc[mi][ni], 0, 0, 0);
            __syncthreads();
        }

        float basev[4], w2v[4];
#pragma unroll
        for (int ni = 0; ni < 4; ni++) {
            int n = wn + ni * 16 + ccol;
            float bb = p.br1[n];
#pragma unroll
            for (int kc = 0; kc < 12; kc++)
                bb += p.basep[((size_t)kc * 32 + b) * 256 + n];
            basev[ni] = bb;
            w2v[ni] = p.Wr2[n];
        }
#pragma unroll
        for (int mi = 0; mi < 4; mi++) {
#pragma unroll
            for (int r = 0; r < 4; r++) {
                float pv = 0.f;
#pragma unroll
                for (int ni = 0; ni < 4; ni++)
                    pv += fmaxf(acc[mi][ni][r] + basev[ni], 0.f) * w2v[ni];
                for (int msk = 1; msk < 16; msk <<= 1)
                    pv += __shfl_xor(pv, msk, 64);
                if ((lane & 15) == 0)
                    sm.p4.sred[mi * 16 + crow + r][wave] = pv;
            }
        }
        __syncthreads();
        if (tid < 64) {
            float s = sm.p4.sred[tid][0] + sm.p4.sred[tid][1] + sm.p4.sred[tid][2] +
                      sm.p4.sred[tid][3] + p.br2[0];
            p.out[(size_t)b * PP + p0 + tid] = s;
        }
    }
}

// ---------------------------------------------------------------------------
extern "C" void kernel_launch(void* const* d_in, const int* in_sizes, int n_in,
                              void* d_out, int out_size, void* d_ws, size_t ws_size,
                              hipStream_t stream) {
    (void)in_sizes; (void)n_in; (void)out_size; (void)ws_size;
    const float* seq      = (const float*)d_in[0];
    const int*   starts   = (const int*)d_in[1];
    const int*   types    = (const int*)d_in[2];
    const int*   pair_idx = (const int*)d_in[3];
    const int*   rel_ids  = (const int*)d_in[4];
    const float* temb     = (const float*)d_in[5];
    const float* remb     = (const float*)d_in[6];
    const float* W1       = (const float*)d_in[7];
    const float* a_src1   = (const float*)d_in[8];
    const float* a_dst1   = (const float*)d_in[9];
    const float* b1       = (const float*)d_in[10];
    const float* ln1_g    = (const float*)d_in[11];
    const float* ln1_b    = (const float*)d_in[12];
    const float* W2       = (const float*)d_in[13];
    const float* a_src2   = (const float*)d_in[14];
    const float* a_dst2   = (const float*)d_in[15];
    const float* b2       = (const float*)d_in[16];
    const float* ln2_g    = (const float*)d_in[17];
    const float* ln2_b    = (const float*)d_in[18];
    const float* Wr1      = (const float*)d_in[19];
    const float* br1      = (const float*)d_in[20];
    const float* Wr2      = (const float*)d_in[21];
    const float* br2      = (const float*)d_in[22];
    float* out = (float*)d_out;

    unsigned short* xb    = (unsigned short*)d_ws;        // 4096*768
    unsigned short* Wt    = xb + (size_t)4096 * 768;      // 256*768
    unsigned short* Wtr   = Wt + (size_t)256 * 768;       // 256*160
    unsigned short* W2t   = Wtr + (size_t)256 * 160;      // 64*256
    unsigned short* rembb = W2t + (size_t)64 * 256;       // 512
    unsigned short* h1Tg  = rembb + 512;                  // 4096*256 (32*2*128*128)
    unsigned short* h2Tg  = h1Tg + (size_t)4096 * 256;    // 32*64*128
    unsigned short* x2b   = h2Tg + (size_t)32 * 64 * 128; // 4096*64
    float* fbase = (float*)(x2b + (size_t)4096 * 64);
    float* ps_s  = fbase;                      // 2*8192
    float* ps_d  = ps_s + 2 * 8192;            // 2*8192
    float* s2    = ps_d + 2 * 8192;            // 4096
    float* d2    = s2 + 4096;                  // 4096
    float* basep = d2 + 4096;                  // 12*32*256

    pool_prep_kernel<<<BB * EE + 75 + 12 * 32, 256, 0, stream>>>(
        seq, starts, types, temb, xb, W1, Wt, Wr1, Wtr, W2, W2t, remb, rembb,
        basep);

    FusedParams fp;
    fp.Xb = xb; fp.Wt = Wt; fp.asrc1 = a_src1; fp.adst1 = a_dst1;
    fp.h1Tg = h1Tg; fp.ps_s = ps_s; fp.ps_d = ps_d;
    fp.b1 = b1; fp.ln1g = ln1_g; fp.ln1b = ln1_b;
    fp.W2t = W2t; fp.asrc2 = a_src2; fp.adst2 = a_dst2;
    fp.h2Tg = h2Tg; fp.s2 = s2; fp.d2 = d2;
    fp.b2v = b2; fp.ln2g = ln2_g; fp.ln2b = ln2_b;
    fp.x2b = x2b; fp.basep = basep; fp.br1 = br1;
    fp.pair_idx = pair_idx; fp.rel_ids = rel_ids;
    fp.rembb = rembb; fp.Wtr = Wtr; fp.Wr2 = Wr2; fp.br2 = br2;
    fp.out = out;
    void* kargs[] = { (void*)&fp };
    hipLaunchCooperativeKernel((const void*)fused_mid_kernel, dim3(256), dim3(256),
                               kargs, 0, stream);
}

// Round 4
// 238.368 us; speedup vs baseline: 1.5522x; 1.5522x over previous
//
#include <hip/hip_runtime.h>
#include <hip/hip_bf16.h>

#define BB 32
#define SS 1024
#define HHH 768
#define EE 128
#define WW 8
#define PP 512
#define RDD 32

typedef __attribute__((ext_vector_type(8))) short bf16x8;
typedef __attribute__((ext_vector_type(8))) unsigned short us8;
typedef __attribute__((ext_vector_type(4))) unsigned short us4;
typedef __attribute__((ext_vector_type(4))) float f32x4;

__device__ __forceinline__ unsigned short f2bf(float v) {
    __hip_bfloat16 h = __float2bfloat16(v);
    return *(unsigned short*)&h;
}

// ---------------------------------------------------------------------------
// K1: merged pool + prep (unchanged).
// ---------------------------------------------------------------------------
__global__ __launch_bounds__(256) void pool_prep_kernel(
    const float* __restrict__ seq, const int* __restrict__ starts,
    const int* __restrict__ types, const float* __restrict__ temb,
    unsigned short* __restrict__ xout,
    const float* __restrict__ W1, unsigned short* __restrict__ Wt,
    const float* __restrict__ Wr1, unsigned short* __restrict__ Wtr,
    const float* __restrict__ W2, unsigned short* __restrict__ W2t,
    const float* __restrict__ remb, unsigned short* __restrict__ rembb,
    float* __restrict__ basep) {
    int tid = threadIdx.x;
    __shared__ float sbuf[WW * HHH];
    __shared__ float scred[WW];
    __shared__ float attn_s[WW];

    if (blockIdx.x < BB * EE) {
        int be = blockIdx.x;
        int b = be >> 7;
        int start = starts[be];
        const float4* bp4 = (const float4*)(seq + ((size_t)b * SS + start) * HHH);
        for (int idx = tid; idx < WW * (HHH / 4); idx += 256) {
            int w = idx / (HHH / 4), h4 = idx % (HHH / 4);
            float4 v = bp4[(size_t)w * (HHH / 4) + h4];
            sbuf[w * HHH + h4 * 4 + 0] = v.x; sbuf[w * HHH + h4 * 4 + 1] = v.y;
            sbuf[w * HHH + h4 * 4 + 2] = v.z; sbuf[w * HHH + h4 * 4 + 3] = v.w;
        }
        __syncthreads();

        float sc[WW];
#pragma unroll
        for (int w = 0; w < WW; w++) sc[w] = 0.f;
#pragma unroll
        for (int c = 0; c < 3; c++) {
            int h = tid + 256 * c;
            float s = 0.f;
#pragma unroll
            for (int w = 0; w < WW; w++) s += sbuf[w * HHH + h];
            float m = s * (1.0f / WW);
#pragma unroll
            for (int w = 0; w < WW; w++) sc[w] += sbuf[w * HHH + h] * m;
        }
        if (tid < WW) scred[tid] = 0.f;
        __syncthreads();
        int lane = tid & 63;
#pragma unroll
        for (int w = 0; w < WW; w++) {
            float v = sc[w];
            for (int o = 32; o > 0; o >>= 1) v += __shfl_down(v, o, 64);
            if (lane == 0) atomicAdd(&scred[w], v);
        }
        __syncthreads();
        if (tid == 0) {
            float mx = scred[0];
            for (int w = 1; w < WW; w++) mx = fmaxf(mx, scred[w]);
            float ssum = 0.f;
            float a[WW];
            for (int w = 0; w < WW; w++) { a[w] = __expf(scred[w] - mx); ssum += a[w]; }
            float inv = 1.f / ssum;
            for (int w = 0; w < WW; w++) attn_s[w] = a[w] * inv;
        }
        __syncthreads();

        int t = types[be];
        const float* emb = temb + (size_t)t * HHH;
#pragma unroll
        for (int c = 0; c < 3; c++) {
            int h = tid + 256 * c;
            float p = 0.f;
#pragma unroll
            for (int w = 0; w < WW; w++) p += attn_s[w] * sbuf[w * HHH + h];
            xout[(size_t)be * HHH + h] = f2bf(p + emb[h]);
        }
        return;
    }

    int blk = blockIdx.x - BB * EE;
    if (blk < 48) {
        int k0 = blk * 16;
        for (int i = tid; i < 16 * 256; i += 256)
            sbuf[i] = W1[(size_t)(k0 + (i >> 8)) * 256 + (i & 255)];
        __syncthreads();
        int n = tid;
        us8 v0, v1;
#pragma unroll
        for (int kk = 0; kk < 8; kk++) v0[kk] = f2bf(sbuf[kk * 256 + n]);
#pragma unroll
        for (int kk = 0; kk < 8; kk++) v1[kk] = f2bf(sbuf[(8 + kk) * 256 + n]);
        *(us8*)(Wt + (size_t)n * HHH + k0) = v0;
        *(us8*)(Wt + (size_t)n * HHH + k0 + 8) = v1;
    } else if (blk < 58) {
        int k0 = (blk - 48) * 16;
        for (int i = tid; i < 16 * 256; i += 256)
            sbuf[i] = Wr1[(size_t)(k0 + (i >> 8)) * 256 + (i & 255)];
        __syncthreads();
        int n = tid;
        us8 v0, v1;
#pragma unroll
        for (int kk = 0; kk < 8; kk++) v0[kk] = f2bf(sbuf[kk * 256 + n]);
#pragma unroll
        for (int kk = 0; kk < 8; kk++) v1[kk] = f2bf(sbuf[(8 + kk) * 256 + n]);
        *(us8*)(Wtr + (size_t)n * 160 + k0) = v0;
        *(us8*)(Wtr + (size_t)n * 160 + k0 + 8) = v1;
    } else if (blk < 74) {
        int k0 = (blk - 58) * 16;
        for (int i = tid; i < 16 * 64; i += 256)
            sbuf[(i >> 6) * 64 + (i & 63)] = W2[(size_t)(k0 + (i >> 6)) * 64 + (i & 63)];
        __syncthreads();
        if (tid < 64) {
            int n = tid;
            us8 v0, v1;
#pragma unroll
            for (int kk = 0; kk < 8; kk++) v0[kk] = f2bf(sbuf[kk * 64 + n]);
#pragma unroll
            for (int kk = 0; kk < 8; kk++) v1[kk] = f2bf(sbuf[(8 + kk) * 64 + n]);
            *(us8*)(W2t + (size_t)n * 256 + k0) = v0;
            *(us8*)(W2t + (size_t)n * 256 + k0 + 8) = v1;
        }
    } else if (blk == 74) {
        for (int i = tid; i < 9 * RDD; i += 256) rembb[i] = f2bf(remb[i]);
    } else {
        int pc = blk - 75;
        int kc = pc % 12;
        int b = pc / 12;
        int n = tid;
        if (n < 64) sbuf[4096 + n] = seq[(size_t)b * SS * HHH + kc * 64 + n];
        __syncthreads();
        float acc = 0.f;
        const float* w = Wr1 + (size_t)(160 + kc * 64) * 256 + n;
#pragma unroll 16
        for (int k = 0; k < 64; k++) acc += sbuf[4096 + k] * w[(size_t)k * 256];
        basep[((size_t)kc * 32 + b) * 256 + n] = acc;
    }
}

// ---------------------------------------------------------------------------
// K2: GEMM1 via MFMA bf16, fused sd1 partial dots + bf16 transposed output.
// (unchanged from round 1)
// ---------------------------------------------------------------------------
__global__ __launch_bounds__(256) void gemm1_mfma_kernel(
    const unsigned short* __restrict__ Xb, const unsigned short* __restrict__ Wt,
    const float* __restrict__ asrc1, const float* __restrict__ adst1,
    unsigned short* __restrict__ h1Tg,
    float* __restrict__ ps_s, float* __restrict__ ps_d) {
    const int K = HHH;
    int n0 = blockIdx.x * 64;
    int m0 = blockIdx.y * 64;
    int tid = threadIdx.x;
    int wave = tid >> 6, lane = tid & 63;
    int wm = (wave >> 1) * 32, wn = (wave & 1) * 32;

    __shared__ __align__(16) unsigned short As[64][40];
    __shared__ __align__(16) unsigned short Bs[64][40];
    __shared__ __align__(16) unsigned short T[64][72];
    __shared__ float sdred[64][2][2];

    f32x4 acc[2][2] = {};
    int ar = tid >> 2;
    int ac = (tid & 3) * 8;
    int fr = lane & 15;
    int fk = (lane >> 4) * 8;

    for (int k0 = 0; k0 < K; k0 += 32) {
        us8 av = *(const us8*)(Xb + (size_t)(m0 + ar) * K + k0 + ac);
        us8 bv = *(const us8*)(Wt + (size_t)(n0 + ar) * K + k0 + ac);
        *(us8*)(&As[ar][ac]) = av;
        *(us8*)(&Bs[ar][ac]) = bv;
        __syncthreads();

        bf16x8 a0 = *(const bf16x8*)(&As[wm + fr][fk]);
        bf16x8 a1 = *(const bf16x8*)(&As[wm + 16 + fr][fk]);
        bf16x8 b0 = *(const bf16x8*)(&Bs[wn + fr][fk]);
        bf16x8 b1 = *(const bf16x8*)(&Bs[wn + 16 + fr][fk]);

        acc[0][0] = __builtin_amdgcn_mfma_f32_16x16x32_bf16(a0, b0, acc[0][0], 0, 0, 0);
        acc[0][1] = __builtin_amdgcn_mfma_f32_16x16x32_bf16(a0, b1, acc[0][1], 0, 0, 0);
        acc[1][0] = __builtin_amdgcn_mfma_f32_16x16x32_bf16(a1, b0, acc[1][0], 0, 0, 0);
        acc[1][1] = __builtin_amdgcn_mfma_f32_16x16x32_bf16(a1, b1, acc[1][1], 0, 0, 0);
        __syncthreads();
    }

    int crow = (lane >> 4) * 4;
    int ccol = lane & 15;
    int h = n0 >> 7;
    int nb = (n0 >> 6) & 1;
    int dbase = (n0 & 127) + wn;

    float asv[2], adv[2];
#pragma unroll
    for (int ni = 0; ni < 2; ni++) {
        int d = dbase + ni * 16 + ccol;
        asv[ni] = asrc1[h * 128 + d];
        adv[ni] = adst1[h * 128 + d];
    }

#pragma unroll
    for (int mi = 0; mi < 2; mi++) {
#pragma unroll
        for (int r = 0; r < 4; r++) {
            float sp = 0.f, dp = 0.f;
#pragma unroll
            for (int ni = 0; ni < 2; ni++) {
                float v = acc[mi][ni][r];
                T[wn + ni * 16 + ccol][wm + mi * 16 + crow + r] = f2bf(v);
                sp += v * asv[ni];
                dp += v * adv[ni];
            }
            for (int msk = 1; msk < 16; msk <<= 1) {
                sp += __shfl_xor(sp, msk, 64);
                dp += __shfl_xor(dp, msk, 64);
            }
            if ((lane & 15) == 0) {
                int row = wm + mi * 16 + crow + r;
                sdred[row][wn >> 5][0] = sp;
                sdred[row][wn >> 5][1] = dp;
            }
        }
    }
    __syncthreads();

    int b = m0 >> 7;
    int j0 = m0 & 127;
    if (tid < 64) {
        float spt = sdred[tid][0][0] + sdred[tid][1][0];
        float dpt = sdred[tid][0][1] + sdred[tid][1][1];
        size_t o = (size_t)nb * 8192 + ((size_t)(m0 + tid)) * 2 + h;
        ps_s[o] = spt;
        ps_d[o] = dpt;
    }
    {
        int d_l = tid >> 2, q = tid & 3;
        us8 v0 = *(const us8*)(&T[d_l][q * 16]);
        us8 v1 = *(const us8*)(&T[d_l][q * 16 + 8]);
        size_t go = ((size_t)(b * 2 + h) * 128 + (n0 & 127) + d_l) * 128 + j0 + q * 16;
        *(us8*)(h1Tg + go) = v0;
        *(us8*)(h1Tg + go + 8) = v1;
    }
}

// ---------------------------------------------------------------------------
// K3: gat_all — GAT1+LN+GEMM2+sd2+GAT2+LN+score, fully block-local per batch.
// grid = 256 blocks (8 per b; each redundantly computes the GAT chain for its
// b in LDS, then scores its own 64-pair slice). 1024 threads = 16 waves.
// ---------------------------------------------------------------------------
struct RAu {
    union {
        unsigned short h1T[128][136];                 // PV staging (per head)
        struct {
            unsigned short t2[64][136];               // h2 transposed [d][j]
            float sred[64][16];                       // P4 partial sums
        } s;
    };
};
struct RBu {
    union {
        unsigned short g1s[128][264];                 // LN'd GAT1 output
        struct {
            unsigned short As[64][168];               // P4 pair features
            unsigned short Bs[256][40];               // P4 Wtr k-chunk
        } s;
    };
};

__global__ __launch_bounds__(1024) void gat_all_kernel(
    const unsigned short* __restrict__ h1Tg,
    const float* __restrict__ ps_s, const float* __restrict__ ps_d,
    const float* __restrict__ b1, const float* __restrict__ ln1g,
    const float* __restrict__ ln1b,
    const unsigned short* __restrict__ W2t,
    const float* __restrict__ asrc2, const float* __restrict__ adst2,
    const float* __restrict__ b2v, const float* __restrict__ ln2g,
    const float* __restrict__ ln2b,
    const float* __restrict__ basep, const float* __restrict__ br1,
    const int* __restrict__ pair_idx, const int* __restrict__ rel_ids,
    const unsigned short* __restrict__ rembb, const unsigned short* __restrict__ Wtr,
    const float* __restrict__ Wr2, const float* __restrict__ br2,
    float* __restrict__ out) {
    int bid = blockIdx.x;
    int b = bid >> 3;
    int pslice = bid & 7;
    int tid = threadIdx.x;
    int wave = tid >> 6, lane = tid & 63;
    int fr = lane & 15;
    int fk = (lane >> 4) * 8;
    int crow = (lane >> 4) * 4;
    int ccol = lane & 15;

    __shared__ __align__(16) RAu ra;
    __shared__ __align__(16) RBu rb;
    __shared__ __align__(16) unsigned short x2s[128][68];
    __shared__ float ssh[2][128];
    __shared__ float dsh[2][128];
    __shared__ float lnred[128][2][2];
    __shared__ float sdr2[128][2][2];
    __shared__ float s2s[128];
    __shared__ float d2s[128];
    __shared__ int prs[64][3];

    // ---- stage sd1 sums -------------------------------------------------
    if (tid < 256) {
        int hh = tid >> 7, j = tid & 127;
        size_t o = ((size_t)b * 128 + j) * 2 + hh;
        ssh[hh][j] = ps_s[o] + ps_s[o + 8192];
        dsh[hh][j] = ps_d[o] + ps_d[o + 8192];
    }

    // ---- P2: GAT1 softmax + PV, one head per pass -----------------------
    int m8 = wave & 7;      // 16-row fragment (rows m8*16 .. +15)
    int dh = wave >> 3;     // d-half of the head (0: d 0..63, 1: d 64..127)
    f32x4 accH[2][4] = {};

#pragma unroll
    for (int hp = 0; hp < 2; hp++) {
        {
            const us8* src = (const us8*)(h1Tg + ((size_t)(b * 2 + hp) * 128) * 128);
#pragma unroll
            for (int it = 0; it < 2; it++) {
                int i8 = tid + it * 1024;
                int row = i8 >> 4, j8 = i8 & 15;
                *(us8*)(&ra.h1T[row][j8 * 8]) = src[i8];
            }
        }
        __syncthreads();

        bf16x8 afrag[4];
        {
            float dd = dsh[hp][m8 * 16 + fr];
            float ev[4][8];
            float mx = -1e30f;
#pragma unroll
            for (int ks = 0; ks < 4; ks++)
#pragma unroll
                for (int jj = 0; jj < 8; jj++) {
                    float e = dd + ssh[hp][ks * 32 + fk + jj];
                    e = e >= 0.f ? e : 0.2f * e;
                    ev[ks][jj] = e;
                    mx = fmaxf(mx, e);
                }
            mx = fmaxf(mx, __shfl_xor(mx, 16, 64));
            mx = fmaxf(mx, __shfl_xor(mx, 32, 64));
            float sm = 0.f;
#pragma unroll
            for (int ks = 0; ks < 4; ks++)
#pragma unroll
                for (int jj = 0; jj < 8; jj++) {
                    float e = __expf(ev[ks][jj] - mx);
                    ev[ks][jj] = e;
                    sm += e;
                }
            sm += __shfl_xor(sm, 16, 64);
            sm += __shfl_xor(sm, 32, 64);
            float inv = 1.f / sm;
#pragma unroll
            for (int ks = 0; ks < 4; ks++) {
                bf16x8 a;
#pragma unroll
                for (int jj = 0; jj < 8; jj++)
                    a[jj] = (short)f2bf(ev[ks][jj] * inv);
                afrag[ks] = a;
            }
        }

#pragma unroll
        for (int ks = 0; ks < 4; ks++)
#pragma unroll
            for (int ni = 0; ni < 4; ni++) {
                bf16x8 bv = *(const bf16x8*)(&ra.h1T[dh * 64 + ni * 16 + fr][ks * 32 + fk]);
                accH[hp][ni] = __builtin_amdgcn_mfma_f32_16x16x32_bf16(
                    afrag[ks], bv, accH[hp][ni], 0, 0, 0);
            }
        __syncthreads();
    }

    // ---- bias + LN(256) + ELU -> g1s ------------------------------------
    {
        float bv_[2][4], gv[2][4], bev[2][4];
#pragma unroll
        for (int hp = 0; hp < 2; hp++)
#pragma unroll
            for (int ni = 0; ni < 4; ni++) {
                int d = hp * 128 + dh * 64 + ni * 16 + ccol;
                bv_[hp][ni] = b1[d]; gv[hp][ni] = ln1g[d]; bev[hp][ni] = ln1b[d];
            }
        float vv[2][4][4];
#pragma unroll
        for (int r = 0; r < 4; r++) {
            float s = 0.f, q = 0.f;
#pragma unroll
            for (int hp = 0; hp < 2; hp++)
#pragma unroll
                for (int ni = 0; ni < 4; ni++) {
                    float v = accH[hp][ni][r] + bv_[hp][ni];
                    vv[hp][r][ni] = v;
                    s += v;
                    q += v * v;
                }
            s += __shfl_xor(s, 1, 64); s += __shfl_xor(s, 2, 64);
            s += __shfl_xor(s, 4, 64); s += __shfl_xor(s, 8, 64);
            q += __shfl_xor(q, 1, 64); q += __shfl_xor(q, 2, 64);
            q += __shfl_xor(q, 4, 64); q += __shfl_xor(q, 8, 64);
            if ((lane & 15) == 0) {
                lnred[m8 * 16 + crow + r][dh][0] = s;
                lnred[m8 * 16 + crow + r][dh][1] = q;
            }
        }
        __syncthreads();
#pragma unroll
        for (int r = 0; r < 4; r++) {
            int row = m8 * 16 + crow + r;
            float s = lnred[row][0][0] + lnred[row][1][0];
            float q = lnred[row][0][1] + lnred[row][1][1];
            float mean = s * (1.f / 256.f);
            float var = q * (1.f / 256.f) - mean * mean;
            float rs = rsqrtf(var + 1e-5f);
#pragma unroll
            for (int hp = 0; hp < 2; hp++)
#pragma unroll
                for (int ni = 0; ni < 4; ni++) {
                    float y = (vv[hp][r][ni] - mean) * rs * gv[hp][ni] + bev[hp][ni];
                    y = y > 0.f ? y : (__expf(y) - 1.f);
                    rb.g1s[row][hp * 128 + dh * 64 + ni * 16 + ccol] = f2bf(y);
                }
        }
    }
    __syncthreads();

    // ---- GEMM2: g1s(128x256) @ W2t^T(64x256) + sd2 dots -> t2, s2s/d2s --
    {
        int m2 = wave & 7;
        int nh = wave >> 3;
        f32x4 acc2[2] = {};
#pragma unroll
        for (int kc = 0; kc < 8; kc++) {
            bf16x8 a = *(const bf16x8*)(&rb.g1s[m2 * 16 + fr][kc * 32 + fk]);
#pragma unroll
            for (int ni = 0; ni < 2; ni++) {
                bf16x8 wv = *(const bf16x8*)(W2t + (size_t)(nh * 32 + ni * 16 + fr) * 256 +
                                             kc * 32 + fk);
                acc2[ni] = __builtin_amdgcn_mfma_f32_16x16x32_bf16(a, wv, acc2[ni], 0, 0, 0);
            }
        }
        float as2[2], ad2[2];
#pragma unroll
        for (int ni = 0; ni < 2; ni++) {
            int n = nh * 32 + ni * 16 + ccol;
            as2[ni] = asrc2[n];
            ad2[ni] = adst2[n];
        }
#pragma unroll
        for (int r = 0; r < 4; r++) {
            int rl = m2 * 16 + crow + r;
            float sp = 0.f, dp = 0.f;
#pragma unroll
            for (int ni = 0; ni < 2; ni++) {
                float v = acc2[ni][r];
                ra.s.t2[nh * 32 + ni * 16 + ccol][rl] = f2bf(v);
                sp += v * as2[ni];
                dp += v * ad2[ni];
            }
            for (int msk = 1; msk < 16; msk <<= 1) {
                sp += __shfl_xor(sp, msk, 64);
                dp += __shfl_xor(dp, msk, 64);
            }
            if ((lane & 15) == 0) {
                sdr2[rl][nh][0] = sp;
                sdr2[rl][nh][1] = dp;
            }
        }
    }
    __syncthreads();
    if (tid < 128) {
        s2s[tid] = sdr2[tid][0][0] + sdr2[tid][1][0];
        d2s[tid] = sdr2[tid][0][1] + sdr2[tid][1][1];
    }
    __syncthreads();

    // ---- P3: GAT2 softmax + PV + LN(64) + ELU -> x2s (waves 0..7) -------
    if (wave < 8) {
        int m3 = wave;
        bf16x8 afrag2[4];
        {
            float dd = d2s[m3 * 16 + fr];
            float ev[4][8];
            float mx = -1e30f;
#pragma unroll
            for (int ks = 0; ks < 4; ks++)
#pragma unroll
                for (int jj = 0; jj < 8; jj++) {
                    float e = dd + s2s[ks * 32 + fk + jj];
                    e = e >= 0.f ? e : 0.2f * e;
                    ev[ks][jj] = e;
                    mx = fmaxf(mx, e);
                }
            mx = fmaxf(mx, __shfl_xor(mx, 16, 64));
            mx = fmaxf(mx, __shfl_xor(mx, 32, 64));
            float sm = 0.f;
#pragma unroll
            for (int ks = 0; ks < 4; ks++)
#pragma unroll
                for (int jj = 0; jj < 8; jj++) {
                    float e = __expf(ev[ks][jj] - mx);
                    ev[ks][jj] = e;
                    sm += e;
                }
            sm += __shfl_xor(sm, 16, 64);
            sm += __shfl_xor(sm, 32, 64);
            float inv = 1.f / sm;
#pragma unroll
            for (int ks = 0; ks < 4; ks++) {
                bf16x8 a;
#pragma unroll
                for (int jj = 0; jj < 8; jj++)
                    a[jj] = (short)f2bf(ev[ks][jj] * inv);
                afrag2[ks] = a;
            }
        }

        f32x4 acc3[4] = {};
#pragma unroll
        for (int ks = 0; ks < 4; ks++)
#pragma unroll
            for (int ni = 0; ni < 4; ni++) {
                bf16x8 bv = *(const bf16x8*)(&ra.s.t2[ni * 16 + fr][ks * 32 + fk]);
                acc3[ni] = __builtin_amdgcn_mfma_f32_16x16x32_bf16(
                    afrag2[ks], bv, acc3[ni], 0, 0, 0);
            }

        float bv_[4], gv[4], bev[4];
#pragma unroll
        for (int ni = 0; ni < 4; ni++) {
            int d = ni * 16 + ccol;
            bv_[ni] = b2v[d]; gv[ni] = ln2g[d]; bev[ni] = ln2b[d];
        }
#pragma unroll
        for (int r = 0; r < 4; r++) {
            float v[4];
            float s = 0.f;
#pragma unroll
            for (int ni = 0; ni < 4; ni++) {
                v[ni] = acc3[ni][r] + bv_[ni];
                s += v[ni];
            }
            s += __shfl_xor(s, 1, 64); s += __shfl_xor(s, 2, 64);
            s += __shfl_xor(s, 4, 64); s += __shfl_xor(s, 8, 64);
            float mean = s * (1.f / 64.f);
            float sq = 0.f;
#pragma unroll
            for (int ni = 0; ni < 4; ni++) {
                float dv = v[ni] - mean;
                sq += dv * dv;
            }
            sq += __shfl_xor(sq, 1, 64); sq += __shfl_xor(sq, 2, 64);
            sq += __shfl_xor(sq, 4, 64); sq += __shfl_xor(sq, 8, 64);
            float rs = rsqrtf(sq * (1.f / 64.f) + 1e-5f);
            int i = m3 * 16 + crow + r;
#pragma unroll
            for (int ni = 0; ni < 4; ni++) {
                float y = (v[ni] - mean) * rs * gv[ni] + bev[ni];
                y = y > 0.f ? y : (__expf(y) - 1.f);
                x2s[i][ni * 16 + ccol] = f2bf(y);
            }
        }
    }

    // ---- P4: scores for this block's 64-pair slice ----------------------
    if (tid < 64) {
        int pp = pslice * 64 + tid;
        prs[tid][0] = pair_idx[((size_t)b * PP + pp) * 2 + 0];
        prs[tid][1] = pair_idx[((size_t)b * PP + pp) * 2 + 1];
        prs[tid][2] = rel_ids[(size_t)b * PP + pp];
    }
    __syncthreads();

#pragma unroll
    for (int it = 0; it < 3; it++) {
        int idx = tid + it * 1024;
        if (idx < 2560) {
            int m = idx / 40, c = idx % 40;
            int k0 = c * 4;
            us4 v;
            if (k0 < 64)
                v = *(const us4*)(&x2s[prs[m][0]][k0]);
            else if (k0 < 128)
                v = *(const us4*)(&x2s[prs[m][1]][k0 - 64]);
            else
                v = *(const us4*)(rembb + prs[m][2] * RDD + (k0 - 128));
            *(us4*)(&rb.s.As[m][k0]) = v;
        }
    }

    f32x4 acc4[4] = {};
    for (int kc = 0; kc < 5; kc++) {
        {
            int n = tid >> 2, c = tid & 3;
            *(us8*)(&rb.s.Bs[n][c * 8]) =
                *(const us8*)(Wtr + (size_t)n * 160 + kc * 32 + c * 8);
        }
        __syncthreads();
        bf16x8 a[4];
#pragma unroll
        for (int mi = 0; mi < 4; mi++)
            a[mi] = *(const bf16x8*)(&rb.s.As[mi * 16 + fr][kc * 32 + fk]);
        bf16x8 bv = *(const bf16x8*)(&rb.s.Bs[wave * 16 + fr][fk]);
#pragma unroll
        for (int mi = 0; mi < 4; mi++)
            acc4[mi] = __builtin_amdgcn_mfma_f32_16x16x32_bf16(a[mi], bv, acc4[mi], 0, 0, 0);
        __syncthreads();
    }

    {
        int n = wave * 16 + ccol;
        float bb = br1[n];
#pragma unroll
        for (int kc = 0; kc < 12; kc++)
            bb += basep[((size_t)kc * 32 + b) * 256 + n];
        float w2v = Wr2[n];
#pragma unroll
        for (int mi = 0; mi < 4; mi++)
#pragma unroll
            for (int r = 0; r < 4; r++) {
                float pv = fmaxf(acc4[mi][r] + bb, 0.f) * w2v;
                pv += __shfl_xor(pv, 1, 64);
                pv += __shfl_xor(pv, 2, 64);
                pv += __shfl_xor(pv, 4, 64);
                pv += __shfl_xor(pv, 8, 64);
                if ((lane & 15) == 0)
                    ra.s.sred[mi * 16 + crow + r][wave] = pv;
            }
    }
    __syncthreads();
    if (tid < 64) {
        float s = br2[0];
#pragma unroll
        for (int w = 0; w < 16; w++) s += ra.s.sred[tid][w];
        out[(size_t)b * PP + pslice * 64 + tid] = s;
    }
}

// ---------------------------------------------------------------------------
extern "C" void kernel_launch(void* const* d_in, const int* in_sizes, int n_in,
                              void* d_out, int out_size, void* d_ws, size_t ws_size,
                              hipStream_t stream) {
    (void)in_sizes; (void)n_in; (void)out_size; (void)ws_size;
    const float* seq      = (const float*)d_in[0];
    const int*   starts   = (const int*)d_in[1];
    const int*   types    = (const int*)d_in[2];
    const int*   pair_idx = (const int*)d_in[3];
    const int*   rel_ids  = (const int*)d_in[4];
    const float* temb     = (const float*)d_in[5];
    const float* remb     = (const float*)d_in[6];
    const float* W1       = (const float*)d_in[7];
    const float* a_src1   = (const float*)d_in[8];
    const float* a_dst1   = (const float*)d_in[9];
    const float* b1       = (const float*)d_in[10];
    const float* ln1_g    = (const float*)d_in[11];
    const float* ln1_b    = (const float*)d_in[12];
    const float* W2       = (const float*)d_in[13];
    const float* a_src2   = (const float*)d_in[14];
    const float* a_dst2   = (const float*)d_in[15];
    const float* b2       = (const float*)d_in[16];
    const float* ln2_g    = (const float*)d_in[17];
    const float* ln2_b    = (const float*)d_in[18];
    const float* Wr1      = (const float*)d_in[19];
    const float* br1      = (const float*)d_in[20];
    const float* Wr2      = (const float*)d_in[21];
    const float* br2      = (const float*)d_in[22];
    float* out = (float*)d_out;

    unsigned short* xb    = (unsigned short*)d_ws;        // 4096*768
    unsigned short* Wt    = xb + (size_t)4096 * 768;      // 256*768
    unsigned short* Wtr   = Wt + (size_t)256 * 768;       // 256*160
    unsigned short* W2t   = Wtr + (size_t)256 * 160;      // 64*256
    unsigned short* rembb = W2t + (size_t)64 * 256;       // 512
    unsigned short* h1Tg  = rembb + 512;                  // 4096*256
    float* fbase = (float*)(h1Tg + (size_t)4096 * 256);
    float* ps_s  = fbase;                      // 2*8192
    float* ps_d  = ps_s + 2 * 8192;            // 2*8192
    float* basep = ps_d + 2 * 8192;            // 12*32*256

    pool_prep_kernel<<<BB * EE + 75 + 12 * 32, 256, 0, stream>>>(
        seq, starts, types, temb, xb, W1, Wt, Wr1, Wtr, W2, W2t, remb, rembb,
        basep);
    gemm1_mfma_kernel<<<dim3(4, 64), 256, 0, stream>>>(xb, Wt, a_src1, a_dst1,
                                                       h1Tg, ps_s, ps_d);
    gat_all_kernel<<<256, 1024, 0, stream>>>(
        h1Tg, ps_s, ps_d, b1, ln1_g, ln1_b, W2t, a_src2, a_dst2,
        b2, ln2_g, ln2_b, basep, br1, pair_idx, rel_ids, rembb, Wtr,
        Wr2, br2, out);
}

// Round 5
// 229.259 us; speedup vs baseline: 1.6139x; 1.0397x over previous
//
#include <hip/hip_runtime.h>
#include <hip/hip_bf16.h>

#define BB 32
#define SS 1024
#define HHH 768
#define EE 128
#define WW 8
#define PP 512
#define RDD 32

typedef __attribute__((ext_vector_type(8))) short bf16x8;
typedef __attribute__((ext_vector_type(8))) unsigned short us8;
typedef __attribute__((ext_vector_type(4))) unsigned short us4;
typedef __attribute__((ext_vector_type(4))) float f32x4;

__device__ __forceinline__ unsigned short f2bf(float v) {
    __hip_bfloat16 h = __float2bfloat16(v);
    return *(unsigned short*)&h;
}

// ---------------------------------------------------------------------------
// K1: merged pool + prep (unchanged, verified R1).
// ---------------------------------------------------------------------------
__global__ __launch_bounds__(256) void pool_prep_kernel(
    const float* __restrict__ seq, const int* __restrict__ starts,
    const int* __restrict__ types, const float* __restrict__ temb,
    unsigned short* __restrict__ xout,
    const float* __restrict__ W1, unsigned short* __restrict__ Wt,
    const float* __restrict__ Wr1, unsigned short* __restrict__ Wtr,
    const float* __restrict__ W2, unsigned short* __restrict__ W2t,
    const float* __restrict__ remb, unsigned short* __restrict__ rembb,
    float* __restrict__ basep) {
    int tid = threadIdx.x;
    __shared__ float sbuf[WW * HHH];
    __shared__ float scred[WW];
    __shared__ float attn_s[WW];

    if (blockIdx.x < BB * EE) {
        int be = blockIdx.x;
        int b = be >> 7;
        int start = starts[be];
        const float4* bp4 = (const float4*)(seq + ((size_t)b * SS + start) * HHH);
        for (int idx = tid; idx < WW * (HHH / 4); idx += 256) {
            int w = idx / (HHH / 4), h4 = idx % (HHH / 4);
            float4 v = bp4[(size_t)w * (HHH / 4) + h4];
            sbuf[w * HHH + h4 * 4 + 0] = v.x; sbuf[w * HHH + h4 * 4 + 1] = v.y;
            sbuf[w * HHH + h4 * 4 + 2] = v.z; sbuf[w * HHH + h4 * 4 + 3] = v.w;
        }
        __syncthreads();

        float sc[WW];
#pragma unroll
        for (int w = 0; w < WW; w++) sc[w] = 0.f;
#pragma unroll
        for (int c = 0; c < 3; c++) {
            int h = tid + 256 * c;
            float s = 0.f;
#pragma unroll
            for (int w = 0; w < WW; w++) s += sbuf[w * HHH + h];
            float m = s * (1.0f / WW);
#pragma unroll
            for (int w = 0; w < WW; w++) sc[w] += sbuf[w * HHH + h] * m;
        }
        if (tid < WW) scred[tid] = 0.f;
        __syncthreads();
        int lane = tid & 63;
#pragma unroll
        for (int w = 0; w < WW; w++) {
            float v = sc[w];
            for (int o = 32; o > 0; o >>= 1) v += __shfl_down(v, o, 64);
            if (lane == 0) atomicAdd(&scred[w], v);
        }
        __syncthreads();
        if (tid == 0) {
            float mx = scred[0];
            for (int w = 1; w < WW; w++) mx = fmaxf(mx, scred[w]);
            float ssum = 0.f;
            float a[WW];
            for (int w = 0; w < WW; w++) { a[w] = __expf(scred[w] - mx); ssum += a[w]; }
            float inv = 1.f / ssum;
            for (int w = 0; w < WW; w++) attn_s[w] = a[w] * inv;
        }
        __syncthreads();

        int t = types[be];
        const float* emb = temb + (size_t)t * HHH;
#pragma unroll
        for (int c = 0; c < 3; c++) {
            int h = tid + 256 * c;
            float p = 0.f;
#pragma unroll
            for (int w = 0; w < WW; w++) p += attn_s[w] * sbuf[w * HHH + h];
            xout[(size_t)be * HHH + h] = f2bf(p + emb[h]);
        }
        return;
    }

    int blk = blockIdx.x - BB * EE;
    if (blk < 48) {
        int k0 = blk * 16;
        for (int i = tid; i < 16 * 256; i += 256)
            sbuf[i] = W1[(size_t)(k0 + (i >> 8)) * 256 + (i & 255)];
        __syncthreads();
        int n = tid;
        us8 v0, v1;
#pragma unroll
        for (int kk = 0; kk < 8; kk++) v0[kk] = f2bf(sbuf[kk * 256 + n]);
#pragma unroll
        for (int kk = 0; kk < 8; kk++) v1[kk] = f2bf(sbuf[(8 + kk) * 256 + n]);
        *(us8*)(Wt + (size_t)n * HHH + k0) = v0;
        *(us8*)(Wt + (size_t)n * HHH + k0 + 8) = v1;
    } else if (blk < 58) {
        int k0 = (blk - 48) * 16;
        for (int i = tid; i < 16 * 256; i += 256)
            sbuf[i] = Wr1[(size_t)(k0 + (i >> 8)) * 256 + (i & 255)];
        __syncthreads();
        int n = tid;
        us8 v0, v1;
#pragma unroll
        for (int kk = 0; kk < 8; kk++) v0[kk] = f2bf(sbuf[kk * 256 + n]);
#pragma unroll
        for (int kk = 0; kk < 8; kk++) v1[kk] = f2bf(sbuf[(8 + kk) * 256 + n]);
        *(us8*)(Wtr + (size_t)n * 160 + k0) = v0;
        *(us8*)(Wtr + (size_t)n * 160 + k0 + 8) = v1;
    } else if (blk < 74) {
        int k0 = (blk - 58) * 16;
        for (int i = tid; i < 16 * 64; i += 256)
            sbuf[(i >> 6) * 64 + (i & 63)] = W2[(size_t)(k0 + (i >> 6)) * 64 + (i & 63)];
        __syncthreads();
        if (tid < 64) {
            int n = tid;
            us8 v0, v1;
#pragma unroll
            for (int kk = 0; kk < 8; kk++) v0[kk] = f2bf(sbuf[kk * 64 + n]);
#pragma unroll
            for (int kk = 0; kk < 8; kk++) v1[kk] = f2bf(sbuf[(8 + kk) * 64 + n]);
            *(us8*)(W2t + (size_t)n * 256 + k0) = v0;
            *(us8*)(W2t + (size_t)n * 256 + k0 + 8) = v1;
        }
    } else if (blk == 74) {
        for (int i = tid; i < 9 * RDD; i += 256) rembb[i] = f2bf(remb[i]);
    } else {
        int pc = blk - 75;
        int kc = pc % 12;
        int b = pc / 12;
        int n = tid;
        if (n < 64) sbuf[4096 + n] = seq[(size_t)b * SS * HHH + kc * 64 + n];
        __syncthreads();
        float acc = 0.f;
        const float* w = Wr1 + (size_t)(160 + kc * 64) * 256 + n;
#pragma unroll 16
        for (int k = 0; k < 64; k++) acc += sbuf[4096 + k] * w[(size_t)k * 256];
        basep[((size_t)kc * 32 + b) * 256 + n] = acc;
    }
}

// ---------------------------------------------------------------------------
// K2: GEMM1 via MFMA bf16, fused sd1 partial dots + bf16 transposed output.
// (unchanged, verified R1)
// ---------------------------------------------------------------------------
__global__ __launch_bounds__(256) void gemm1_mfma_kernel(
    const unsigned short* __restrict__ Xb, const unsigned short* __restrict__ Wt,
    const float* __restrict__ asrc1, const float* __restrict__ adst1,
    unsigned short* __restrict__ h1Tg,
    float* __restrict__ ps_s, float* __restrict__ ps_d) {
    const int K = HHH;
    int n0 = blockIdx.x * 64;
    int m0 = blockIdx.y * 64;
    int tid = threadIdx.x;
    int wave = tid >> 6, lane = tid & 63;
    int wm = (wave >> 1) * 32, wn = (wave & 1) * 32;

    __shared__ __align__(16) unsigned short As[64][40];
    __shared__ __align__(16) unsigned short Bs[64][40];
    __shared__ __align__(16) unsigned short T[64][72];
    __shared__ float sdred[64][2][2];

    f32x4 acc[2][2] = {};
    int ar = tid >> 2;
    int ac = (tid & 3) * 8;
    int fr = lane & 15;
    int fk = (lane >> 4) * 8;

    for (int k0 = 0; k0 < K; k0 += 32) {
        us8 av = *(const us8*)(Xb + (size_t)(m0 + ar) * K + k0 + ac);
        us8 bv = *(const us8*)(Wt + (size_t)(n0 + ar) * K + k0 + ac);
        *(us8*)(&As[ar][ac]) = av;
        *(us8*)(&Bs[ar][ac]) = bv;
        __syncthreads();

        bf16x8 a0 = *(const bf16x8*)(&As[wm + fr][fk]);
        bf16x8 a1 = *(const bf16x8*)(&As[wm + 16 + fr][fk]);
        bf16x8 b0 = *(const bf16x8*)(&Bs[wn + fr][fk]);
        bf16x8 b1 = *(const bf16x8*)(&Bs[wn + 16 + fr][fk]);

        acc[0][0] = __builtin_amdgcn_mfma_f32_16x16x32_bf16(a0, b0, acc[0][0], 0, 0, 0);
        acc[0][1] = __builtin_amdgcn_mfma_f32_16x16x32_bf16(a0, b1, acc[0][1], 0, 0, 0);
        acc[1][0] = __builtin_amdgcn_mfma_f32_16x16x32_bf16(a1, b0, acc[1][0], 0, 0, 0);
        acc[1][1] = __builtin_amdgcn_mfma_f32_16x16x32_bf16(a1, b1, acc[1][1], 0, 0, 0);
        __syncthreads();
    }

    int crow = (lane >> 4) * 4;
    int ccol = lane & 15;
    int h = n0 >> 7;
    int nb = (n0 >> 6) & 1;
    int dbase = (n0 & 127) + wn;

    float asv[2], adv[2];
#pragma unroll
    for (int ni = 0; ni < 2; ni++) {
        int d = dbase + ni * 16 + ccol;
        asv[ni] = asrc1[h * 128 + d];
        adv[ni] = adst1[h * 128 + d];
    }

#pragma unroll
    for (int mi = 0; mi < 2; mi++) {
#pragma unroll
        for (int r = 0; r < 4; r++) {
            float sp = 0.f, dp = 0.f;
#pragma unroll
            for (int ni = 0; ni < 2; ni++) {
                float v = acc[mi][ni][r];
                T[wn + ni * 16 + ccol][wm + mi * 16 + crow + r] = f2bf(v);
                sp += v * asv[ni];
                dp += v * adv[ni];
            }
            for (int msk = 1; msk < 16; msk <<= 1) {
                sp += __shfl_xor(sp, msk, 64);
                dp += __shfl_xor(dp, msk, 64);
            }
            if ((lane & 15) == 0) {
                int row = wm + mi * 16 + crow + r;
                sdred[row][wn >> 5][0] = sp;
                sdred[row][wn >> 5][1] = dp;
            }
        }
    }
    __syncthreads();

    int b = m0 >> 7;
    int j0 = m0 & 127;
    if (tid < 64) {
        float spt = sdred[tid][0][0] + sdred[tid][1][0];
        float dpt = sdred[tid][0][1] + sdred[tid][1][1];
        size_t o = (size_t)nb * 8192 + ((size_t)(m0 + tid)) * 2 + h;
        ps_s[o] = spt;
        ps_d[o] = dpt;
    }
    {
        int d_l = tid >> 2, q = tid & 3;
        us8 v0 = *(const us8*)(&T[d_l][q * 16]);
        us8 v1 = *(const us8*)(&T[d_l][q * 16 + 8]);
        size_t go = ((size_t)(b * 2 + h) * 128 + (n0 & 127) + d_l) * 128 + j0 + q * 16;
        *(us8*)(h1Tg + go) = v0;
        *(us8*)(h1Tg + go + 8) = v1;
    }
}

// ---------------------------------------------------------------------------
// K3: GAT1 fused + GEMM2 + sd2, grid = 32 b x 4 i-chunks = 128 blocks.
// (unchanged, verified R1)
// ---------------------------------------------------------------------------
__global__ __launch_bounds__(256) void gat1_gemm2_kernel(
    const unsigned short* __restrict__ h1Tg,
    const float* __restrict__ ps_s, const float* __restrict__ ps_d,
    const float* __restrict__ b1, const float* __restrict__ gamma,
    const float* __restrict__ beta,
    const unsigned short* __restrict__ W2t,
    const float* __restrict__ asrc2, const float* __restrict__ adst2,
    unsigned short* __restrict__ h2Tg, float* __restrict__ s2,
    float* __restrict__ d2) {
    int b = blockIdx.x >> 2;
    int c = blockIdx.x & 3;
    int tid = threadIdx.x;
    int wave = tid >> 6, lane = tid & 63;
    int h = wave >> 1, m = wave & 1;
    int fr = lane & 15;
    int fk = (lane >> 4) * 8;

    __shared__ __align__(16) unsigned short h1T[2][128][136];
    __shared__ float ssh[2][128];
    __shared__ float dsh[2][128];
    __shared__ float lnred[32][2][2];
    __shared__ __align__(16) unsigned short g1s[32][264];
    __shared__ float sdr2[32][2][2];
    __shared__ __align__(16) unsigned short t2[64][40];

    {
        const us8* src = (const us8*)(h1Tg + (size_t)b * 32768);
#pragma unroll
        for (int it = 0; it < 16; it++) {
            int i8 = tid + it * 256;
            int row = i8 >> 4;
            int j8 = i8 & 15;
            *(us8*)(&h1T[row >> 7][row & 127][j8 * 8]) = src[i8];
        }
        int hh = tid >> 7, j = tid & 127;
        size_t o = ((size_t)b * 128 + j) * 2 + hh;
        ssh[hh][j] = ps_s[o] + ps_s[o + 8192];
        dsh[hh][j] = ps_d[o] + ps_d[o + 8192];
    }
    __syncthreads();

    bf16x8 afrag[4];
    {
        float dd = dsh[h][c * 32 + m * 16 + fr];
        float ev[4][8];
        float mx = -1e30f;
#pragma unroll
        for (int ks = 0; ks < 4; ks++)
#pragma unroll
            for (int jj = 0; jj < 8; jj++) {
                float e = dd + ssh[h][ks * 32 + fk + jj];
                e = e >= 0.f ? e : 0.2f * e;
                ev[ks][jj] = e;
                mx = fmaxf(mx, e);
            }
        mx = fmaxf(mx, __shfl_xor(mx, 16, 64));
        mx = fmaxf(mx, __shfl_xor(mx, 32, 64));
        float sm = 0.f;
#pragma unroll
        for (int ks = 0; ks < 4; ks++)
#pragma unroll
            for (int jj = 0; jj < 8; jj++) {
                float e = __expf(ev[ks][jj] - mx);
                ev[ks][jj] = e;
                sm += e;
            }
        sm += __shfl_xor(sm, 16, 64);
        sm += __shfl_xor(sm, 32, 64);
        float inv = 1.f / sm;
#pragma unroll
        for (int ks = 0; ks < 4; ks++) {
            bf16x8 a;
#pragma unroll
            for (int jj = 0; jj < 8; jj++)
                a[jj] = (short)f2bf(ev[ks][jj] * inv);
            afrag[ks] = a;
        }
    }

    f32x4 acc[8] = {};
#pragma unroll
    for (int ks = 0; ks < 4; ks++)
#pragma unroll
        for (int ni = 0; ni < 8; ni++) {
            bf16x8 bv = *(const bf16x8*)(&h1T[h][ni * 16 + fr][ks * 32 + fk]);
            acc[ni] = __builtin_amdgcn_mfma_f32_16x16x32_bf16(
                afrag[ks], bv, acc[ni], 0, 0, 0);
        }

    int crow = (lane >> 4) * 4;
    int ccol = lane & 15;
    float bv_[8], gv[8], bev[8];
#pragma unroll
    for (int ni = 0; ni < 8; ni++) {
        int d = h * 128 + ni * 16 + ccol;
        bv_[ni] = b1[d]; gv[ni] = gamma[d]; bev[ni] = beta[d];
    }
    float vv[4][8];
#pragma unroll
    for (int r = 0; r < 4; r++) {
        float s = 0.f, q = 0.f;
#pragma unroll
        for (int ni = 0; ni < 8; ni++) {
            float v = acc[ni][r] + bv_[ni];
            vv[r][ni] = v;
            s += v;
            q += v * v;
        }
        s += __shfl_xor(s, 1, 64); s += __shfl_xor(s, 2, 64);
        s += __shfl_xor(s, 4, 64); s += __shfl_xor(s, 8, 64);
        q += __shfl_xor(q, 1, 64); q += __shfl_xor(q, 2, 64);
        q += __shfl_xor(q, 4, 64); q += __shfl_xor(q, 8, 64);
        if ((lane & 15) == 0) {
            lnred[m * 16 + crow + r][h][0] = s;
            lnred[m * 16 + crow + r][h][1] = q;
        }
    }
    __syncthreads();
#pragma unroll
    for (int r = 0; r < 4; r++) {
        int row = m * 16 + crow + r;
        float s = lnred[row][0][0] + lnred[row][1][0];
        float q = lnred[row][0][1] + lnred[row][1][1];
        float mean = s * (1.f / 256.f);
        float var = q * (1.f / 256.f) - mean * mean;
        float rs = rsqrtf(var + 1e-5f);
#pragma unroll
        for (int ni = 0; ni < 8; ni++) {
            float y = (vv[r][ni] - mean) * rs * gv[ni] + bev[ni];
            y = y > 0.f ? y : (__expf(y) - 1.f);
            g1s[row][h * 128 + ni * 16 + ccol] = f2bf(y);
        }
    }
    __syncthreads();

    int m2 = wave & 1;
    int nb = wave >> 1;
    f32x4 acc2[2] = {};
#pragma unroll
    for (int kc = 0; kc < 8; kc++) {
        bf16x8 a = *(const bf16x8*)(&g1s[m2 * 16 + fr][kc * 32 + fk]);
#pragma unroll
        for (int ni = 0; ni < 2; ni++) {
            bf16x8 wv = *(const bf16x8*)(W2t + (size_t)(nb * 32 + ni * 16 + fr) * 256 +
                                         kc * 32 + fk);
            acc2[ni] = __builtin_amdgcn_mfma_f32_16x16x32_bf16(a, wv, acc2[ni], 0, 0, 0);
        }
    }
    float as2[2], ad2[2];
#pragma unroll
    for (int ni = 0; ni < 2; ni++) {
        int n = nb * 32 + ni * 16 + ccol;
        as2[ni] = asrc2[n];
        ad2[ni] = adst2[n];
    }
#pragma unroll
    for (int r = 0; r < 4; r++) {
        int rl = m2 * 16 + crow + r;
        float sp = 0.f, dp = 0.f;
#pragma unroll
        for (int ni = 0; ni < 2; ni++) {
            float v = acc2[ni][r];
            t2[nb * 32 + ni * 16 + ccol][rl] = f2bf(v);
            sp += v * as2[ni];
            dp += v * ad2[ni];
        }
        for (int msk = 1; msk < 16; msk <<= 1) {
            sp += __shfl_xor(sp, msk, 64);
            dp += __shfl_xor(dp, msk, 64);
        }
        if ((lane & 15) == 0) {
            sdr2[rl][nb][0] = sp;
            sdr2[rl][nb][1] = dp;
        }
    }
    __syncthreads();
    if (tid < 32) {
        s2[(size_t)b * 128 + c * 32 + tid] = sdr2[tid][0][0] + sdr2[tid][1][0];
        d2[(size_t)b * 128 + c * 32 + tid] = sdr2[tid][0][1] + sdr2[tid][1][1];
    }
    {
        int d = tid >> 2, q = tid & 3;
        us8 v = *(const us8*)(&t2[d][q * 8]);
        *(us8*)(h2Tg + ((size_t)b * 64 + d) * 128 + c * 32 + q * 8) = v;
    }
}

// ---------------------------------------------------------------------------
// K45: GAT2 (redundant x8, cheap) + 64-pair score, block-local. 256 blocks.
// Phase A = R1's K4 body looped over both 64-row chunks, writing x2s in LDS.
// Phase B = R1's K5 body reading x2s from LDS. LDS union ~60 KB.
// ---------------------------------------------------------------------------
struct K45G {
    unsigned short h2T[64][136];
    float ssh[128];
    float dsh[128];
};
struct K45S {
    unsigned short As[64][168];
    unsigned short Bs[256][40];
    float sred[64][4];
};
union K45U {
    K45G g;
    K45S s;
};

__global__ __launch_bounds__(256) void gat2_score_kernel(
    const unsigned short* __restrict__ h2Tg, const float* __restrict__ s2,
    const float* __restrict__ d2, const float* __restrict__ b2v,
    const float* __restrict__ gamma, const float* __restrict__ beta,
    const float* __restrict__ basep, const float* __restrict__ br1,
    const int* __restrict__ pair_idx, const int* __restrict__ rel_ids,
    const unsigned short* __restrict__ rembb, const unsigned short* __restrict__ Wtr,
    const float* __restrict__ Wr2, const float* __restrict__ br2,
    float* __restrict__ out) {
    int blk = blockIdx.x;
    int b = blk >> 3;
    int p0 = (blk & 7) * 64;
    int tid = threadIdx.x;
    int wave = tid >> 6, lane = tid & 63;
    int fr = lane & 15;
    int fk = (lane >> 4) * 8;
    int crow = (lane >> 4) * 4;
    int ccol = lane & 15;

    __shared__ __align__(16) K45U u;
    __shared__ __align__(16) unsigned short x2s[128][68];
    __shared__ int prs[64][3];

    // ---- Phase A: GAT2 for batch b (redundant across the 8 sibling blocks)
    {
        const us8* src = (const us8*)(h2Tg + (size_t)b * 64 * 128);
#pragma unroll
        for (int it = 0; it < 4; it++) {
            int i8 = tid + it * 256;
            int row = i8 >> 4;
            int j8 = i8 & 15;
            *(us8*)(&u.g.h2T[row][j8 * 8]) = src[i8];
        }
        if (tid < 128) u.g.ssh[tid] = s2[(size_t)b * 128 + tid];
        else u.g.dsh[tid - 128] = d2[(size_t)b * 128 + (tid - 128)];
        if (tid < 64) {
            int pp = p0 + tid;
            prs[tid][0] = pair_idx[((size_t)b * PP + pp) * 2 + 0];
            prs[tid][1] = pair_idx[((size_t)b * PP + pp) * 2 + 1];
            prs[tid][2] = rel_ids[(size_t)b * PP + pp];
        }
    }
    __syncthreads();

#pragma unroll
    for (int c2 = 0; c2 < 2; c2++) {
        bf16x8 afrag[4];
        {
            float dd = u.g.dsh[c2 * 64 + wave * 16 + fr];
            float ev[4][8];
            float mx = -1e30f;
#pragma unroll
            for (int ks = 0; ks < 4; ks++)
#pragma unroll
                for (int jj = 0; jj < 8; jj++) {
                    float e = dd + u.g.ssh[ks * 32 + fk + jj];
                    e = e >= 0.f ? e : 0.2f * e;
                    ev[ks][jj] = e;
                    mx = fmaxf(mx, e);
                }
            mx = fmaxf(mx, __shfl_xor(mx, 16, 64));
            mx = fmaxf(mx, __shfl_xor(mx, 32, 64));
            float sm = 0.f;
#pragma unroll
            for (int ks = 0; ks < 4; ks++)
#pragma unroll
                for (int jj = 0; jj < 8; jj++) {
                    float e = __expf(ev[ks][jj] - mx);
                    ev[ks][jj] = e;
                    sm += e;
                }
            sm += __shfl_xor(sm, 16, 64);
            sm += __shfl_xor(sm, 32, 64);
            float inv = 1.f / sm;
#pragma unroll
            for (int ks = 0; ks < 4; ks++) {
                bf16x8 a;
#pragma unroll
                for (int jj = 0; jj < 8; jj++)
                    a[jj] = (short)f2bf(ev[ks][jj] * inv);
                afrag[ks] = a;
            }
        }

        f32x4 acc[4] = {};
#pragma unroll
        for (int ks = 0; ks < 4; ks++)
#pragma unroll
            for (int ni = 0; ni < 4; ni++) {
                bf16x8 bv = *(const bf16x8*)(&u.g.h2T[ni * 16 + fr][ks * 32 + fk]);
                acc[ni] = __builtin_amdgcn_mfma_f32_16x16x32_bf16(
                    afrag[ks], bv, acc[ni], 0, 0, 0);
            }

        float bv_[4], gv[4], bev[4];
#pragma unroll
        for (int ni = 0; ni < 4; ni++) {
            int d = ni * 16 + ccol;
            bv_[ni] = b2v[d]; gv[ni] = gamma[d]; bev[ni] = beta[d];
        }
#pragma unroll
        for (int r = 0; r < 4; r++) {
            float v[4];
            float s = 0.f;
#pragma unroll
            for (int ni = 0; ni < 4; ni++) {
                v[ni] = acc[ni][r] + bv_[ni];
                s += v[ni];
            }
            s += __shfl_xor(s, 1, 64); s += __shfl_xor(s, 2, 64);
            s += __shfl_xor(s, 4, 64); s += __shfl_xor(s, 8, 64);
            float mean = s * (1.f / 64.f);
            float sq = 0.f;
#pragma unroll
            for (int ni = 0; ni < 4; ni++) {
                float dv = v[ni] - mean;
                sq += dv * dv;
            }
            sq += __shfl_xor(sq, 1, 64); sq += __shfl_xor(sq, 2, 64);
            sq += __shfl_xor(sq, 4, 64); sq += __shfl_xor(sq, 8, 64);
            float rs = rsqrtf(sq * (1.f / 64.f) + 1e-5f);
            int i = c2 * 64 + wave * 16 + crow + r;
#pragma unroll
            for (int ni = 0; ni < 4; ni++) {
                float y = (v[ni] - mean) * rs * gv[ni] + bev[ni];
                y = y > 0.f ? y : (__expf(y) - 1.f);
                x2s[i][ni * 16 + ccol] = f2bf(y);
            }
        }
    }
    __syncthreads();   // x2s complete; u.g no longer read -> u.s may be written

    // ---- Phase B: scores for this block's 64-pair slice -----------------
    for (int it = 0; it < 10; it++) {
        int idx = tid + it * 256;
        int m = idx / 40, c = idx % 40;
        int k0 = c * 4;
        us4 v;
        if (k0 < 64)
            v = *(const us4*)(&x2s[prs[m][0]][k0]);
        else if (k0 < 128)
            v = *(const us4*)(&x2s[prs[m][1]][k0 - 64]);
        else
            v = *(const us4*)(rembb + prs[m][2] * RDD + (k0 - 128));
        *(us4*)(&u.s.As[m][k0]) = v;
    }

    f32x4 acc[4][4] = {};
    int wn = wave * 64;
    for (int kc = 0; kc < 5; kc++) {
        for (int it = 0; it < 4; it++) {
            int i = tid + it * 256;
            int n = i >> 2, c = i & 3;
            *(us8*)(&u.s.Bs[n][c * 8]) =
                *(const us8*)(Wtr + (size_t)n * 160 + kc * 32 + c * 8);
        }
        __syncthreads();
        bf16x8 a[4], bv[4];
#pragma unroll
        for (int mi = 0; mi < 4; mi++)
            a[mi] = *(const bf16x8*)(&u.s.As[mi * 16 + fr][kc * 32 + fk]);
#pragma unroll
        for (int ni = 0; ni < 4; ni++)
            bv[ni] = *(const bf16x8*)(&u.s.Bs[wn + ni * 16 + fr][fk]);
#pragma unroll
        for (int mi = 0; mi < 4; mi++)
#pragma unroll
            for (int ni = 0; ni < 4; ni++)
                acc[mi][ni] = __builtin_amdgcn_mfma_f32_16x16x32_bf16(
                    a[mi], bv[ni], acc[mi][ni], 0, 0, 0);
        __syncthreads();
    }

    float basev[4], w2v[4];
#pragma unroll
    for (int ni = 0; ni < 4; ni++) {
        int n = wn + ni * 16 + ccol;
        float bb = br1[n];
#pragma unroll
        for (int kc = 0; kc < 12; kc++)
            bb += basep[((size_t)kc * 32 + b) * 256 + n];
        basev[ni] = bb;
        w2v[ni] = Wr2[n];
    }
#pragma unroll
    for (int mi = 0; mi < 4; mi++) {
#pragma unroll
        for (int r = 0; r < 4; r++) {
            float p = 0.f;
#pragma unroll
            for (int ni = 0; ni < 4; ni++)
                p += fmaxf(acc[mi][ni][r] + basev[ni], 0.f) * w2v[ni];
            for (int msk = 1; msk < 16; msk <<= 1)
                p += __shfl_xor(p, msk, 64);
            if ((lane & 15) == 0)
                u.s.sred[mi * 16 + crow + r][wave] = p;
        }
    }
    __syncthreads();
    if (tid < 64) {
        float s = u.s.sred[tid][0] + u.s.sred[tid][1] + u.s.sred[tid][2] +
                  u.s.sred[tid][3] + br2[0];
        out[(size_t)b * PP + p0 + tid] = s;
    }
}

// ---------------------------------------------------------------------------
extern "C" void kernel_launch(void* const* d_in, const int* in_sizes, int n_in,
                              void* d_out, int out_size, void* d_ws, size_t ws_size,
                              hipStream_t stream) {
    (void)in_sizes; (void)n_in; (void)out_size; (void)ws_size;
    const float* seq      = (const float*)d_in[0];
    const int*   starts   = (const int*)d_in[1];
    const int*   types    = (const int*)d_in[2];
    const int*   pair_idx = (const int*)d_in[3];
    const int*   rel_ids  = (const int*)d_in[4];
    const float* temb     = (const float*)d_in[5];
    const float* remb     = (const float*)d_in[6];
    const float* W1       = (const float*)d_in[7];
    const float* a_src1   = (const float*)d_in[8];
    const float* a_dst1   = (const float*)d_in[9];
    const float* b1       = (const float*)d_in[10];
    const float* ln1_g    = (const float*)d_in[11];
    const float* ln1_b    = (const float*)d_in[12];
    const float* W2       = (const float*)d_in[13];
    const float* a_src2   = (const float*)d_in[14];
    const float* a_dst2   = (const float*)d_in[15];
    const float* b2       = (const float*)d_in[16];
    const float* ln2_g    = (const float*)d_in[17];
    const float* ln2_b    = (const float*)d_in[18];
    const float* Wr1      = (const float*)d_in[19];
    const float* br1      = (const float*)d_in[20];
    const float* Wr2      = (const float*)d_in[21];
    const float* br2      = (const float*)d_in[22];
    float* out = (float*)d_out;

    unsigned short* xb    = (unsigned short*)d_ws;        // 4096*768
    unsigned short* Wt    = xb + (size_t)4096 * 768;      // 256*768
    unsigned short* Wtr   = Wt + (size_t)256 * 768;       // 256*160
    unsigned short* W2t   = Wtr + (size_t)256 * 160;      // 64*256
    unsigned short* rembb = W2t + (size_t)64 * 256;       // 512
    unsigned short* h1Tg  = rembb + 512;                  // 4096*256
    unsigned short* h2Tg  = h1Tg + (size_t)4096 * 256;    // 32*64*128
    float* fbase = (float*)(h2Tg + (size_t)32 * 64 * 128);
    float* ps_s  = fbase;                      // 2*8192
    float* ps_d  = ps_s + 2 * 8192;            // 2*8192
    float* s2    = ps_d + 2 * 8192;            // 4096
    float* d2    = s2 + 4096;                  // 4096
    float* basep = d2 + 4096;                  // 12*32*256

    pool_prep_kernel<<<BB * EE + 75 + 12 * 32, 256, 0, stream>>>(
        seq, starts, types, temb, xb, W1, Wt, Wr1, Wtr, W2, W2t, remb, rembb,
        basep);
    gemm1_mfma_kernel<<<dim3(4, 64), 256, 0, stream>>>(xb, Wt, a_src1, a_dst1,
                                                       h1Tg, ps_s, ps_d);
    gat1_gemm2_kernel<<<BB * 4, 256, 0, stream>>>(h1Tg, ps_s, ps_d, b1, ln1_g, ln1_b,
                                                  W2t, a_src2, a_dst2, h2Tg, s2, d2);
    gat2_score_kernel<<<BB * PP / 64, 256, 0, stream>>>(
        h2Tg, s2, d2, b2, ln2_g, ln2_b, basep, br1, pair_idx, rel_ids,
        rembb, Wtr, Wr2, br2, out);
}